// Round 5
// baseline (392.776 us; speedup 1.0000x reference)
//
#include <hip/hip_runtime.h>
#include <hip/hip_bf16.h>

#define T_TOKENS 2048
#define D_EMBD 768
#define N_EXP 64
#define EW 256
#define TOPK 8
#define TW (N_EXP*EW)
#define PAD_SLOTS 20480   // 16384 + 64*63 rounded up to 64-tile granularity
#define SCHED_MAX 2560    // 8 * 320 worst-case positions, mult of 512
#define OUT_BASE (2048*768)

typedef __attribute__((ext_vector_type(8))) short bf16x8;
typedef __attribute__((ext_vector_type(4))) float f32x4;

typedef __attribute__((address_space(1))) void GAS;
typedef __attribute__((address_space(3))) void LAS;
#define GLOAD16(g, l) __builtin_amdgcn_global_load_lds((GAS*)(g), (LAS*)(l), 16, 0, 0)

// ---------------- init ----------------
__global__ void k_init(int* counts, int* cursor, float* psum, float* scal,
                       float* wgt_slot, int* tok_slot, int* sched_e) {
  int i = blockIdx.x*256 + threadIdx.x;   // 20480 threads
  if (i < N_EXP) { counts[i] = 0; cursor[i] = 0; psum[i] = 0.f; }
  if (i < 2) scal[i] = 0.f;
  if (i < PAD_SLOTS) { wgt_slot[i] = 0.f; tok_slot[i] = 0; }
  if (i < SCHED_MAX) sched_e[i] = -1;
}

// ---------------- zero FULL out[0 .. T*D) for atomic accumulation ----------------
// T*D = 1,572,864 floats = 393,216 float4  ->  grid 1536 x 256 (one float4/thread).
// (Round-4 bug: grid 384 only zeroed 1/4; atomicAdds accumulated across graph replays.)
__global__ void k_zero_out(float* __restrict__ out) {
  int i = blockIdx.x*256 + threadIdx.x;
  float4 z = {0.f, 0.f, 0.f, 0.f};
  reinterpret_cast<float4*>(out)[i] = z;
}

// ---------------- x -> bf16 ----------------
__global__ void k_cvt_x(const float* __restrict__ x, __hip_bfloat16* __restrict__ xb) {
  int i = blockIdx.x*256 + threadIdx.x;   // 393216 float4
  float4 v = reinterpret_cast<const float4*>(x)[i];
  union { __hip_bfloat16 b; unsigned short u; } c0, c1, c2, c3;
  c0.b = __float2bfloat16(v.x); c1.b = __float2bfloat16(v.y);
  c2.b = __float2bfloat16(v.z); c3.b = __float2bfloat16(v.w);
  ushort4 o; o.x = c0.u; o.y = c1.u; o.z = c2.u; o.w = c3.u;
  reinterpret_cast<ushort4*>(xb)[i] = o;
}

// ---------------- transpose + convert, both weights in one launch ----------------
// z=0: w1 [768][16384] -> w1t [16384][768]; z=1: w2 [16384][768] -> w2t [768][16384]
__global__ __launch_bounds__(256) void k_transpose_cvt(
    const float* __restrict__ s1, __hip_bfloat16* __restrict__ d1,
    const float* __restrict__ s2, __hip_bfloat16* __restrict__ d2) {
  __shared__ float t[64][65];
  const float* src; __hip_bfloat16* dst; int R, C, bx, by;
  if (blockIdx.z == 0) { src = s1; dst = d1; R = 768; C = 16384;
                         bx = blockIdx.x*64; by = blockIdx.y*64; }
  else                 { src = s2; dst = d2; R = 16384; C = 768;
                         bx = blockIdx.y*64; by = blockIdx.x*64; }
  int tid = threadIdx.x;
  int lr = tid >> 4, lc4 = tid & 15;
  #pragma unroll
  for (int i = 0; i < 4; i++) {
    int r = lr + i*16;
    float4 v = *reinterpret_cast<const float4*>(&src[(size_t)(by+r)*C + bx + lc4*4]);
    t[r][lc4*4+0] = v.x; t[r][lc4*4+1] = v.y; t[r][lc4*4+2] = v.z; t[r][lc4*4+3] = v.w;
  }
  __syncthreads();
  int u = tid & 31, c0 = tid >> 5;
  #pragma unroll
  for (int i = 0; i < 8; i++) {
    int c = c0 + i*8;
    union { __hip_bfloat16 b; unsigned short us; } a0, a1;
    a0.b = __float2bfloat16(t[2*u][c]);
    a1.b = __float2bfloat16(t[2*u+1][c]);
    ushort2 o; o.x = a0.us; o.y = a1.us;
    *reinterpret_cast<ushort2*>(&dst[(size_t)(bx+c)*R + by + 2*u]) = o;
  }
}

// ---------------- router logits GEMM: lp[kc][t][e] partial sums ----------------
__global__ __launch_bounds__(256) void k_logits(const float* __restrict__ x,
                                                const float* __restrict__ rw,
                                                float* __restrict__ lp) {
  __shared__ float rw_s[8][256];
  int tid = threadIdx.x;
  int tg = blockIdx.x, eg = blockIdx.y, kc = blockIdx.z;
  #pragma unroll
  for (int idx = 0; idx < 8; idx++)
    rw_s[idx][tid] = rw[(size_t)(eg*8 + idx)*D_EMBD + kc*256 + tid];
  __syncthreads();
  int tok = tg*256 + tid;
  const float4* x4 = reinterpret_cast<const float4*>(x + (size_t)tok*D_EMBD + kc*256);
  float acc[8];
  #pragma unroll
  for (int e = 0; e < 8; e++) acc[e] = 0.f;
  #pragma unroll 4
  for (int k4 = 0; k4 < 64; k4++) {
    float4 xv = x4[k4];
    #pragma unroll
    for (int e = 0; e < 8; e++)
      acc[e] += xv.x*rw_s[e][k4*4+0] + xv.y*rw_s[e][k4*4+1]
              + xv.z*rw_s[e][k4*4+2] + xv.w*rw_s[e][k4*4+3];
  }
  float* dst = lp + (size_t)kc*T_TOKENS*N_EXP + (size_t)tok*N_EXP + eg*8;
  float4 o0 = {acc[0], acc[1], acc[2], acc[3]};
  float4 o1 = {acc[4], acc[5], acc[6], acc[7]};
  reinterpret_cast<float4*>(dst)[0] = o0;
  reinterpret_cast<float4*>(dst)[1] = o1;
}

// ---------------- router part 2: sigmoid, parallel-rank top-8, losses ----------------
__global__ __launch_bounds__(256) void k_router2(const float* __restrict__ lp,
                          int* __restrict__ sel_e, float* __restrict__ sel_w,
                          int* __restrict__ counts, float* __restrict__ psum,
                          float* __restrict__ scal) {
  __shared__ float psum_s[4][64];
  __shared__ int cnt_s[4][64];
  int tid = threadIdx.x, wv = tid >> 6, lane = tid & 63;
  float pacc = 0.f, zacc = 0.f;
  int cacc = 0;
  int tbase = blockIdx.x*8 + wv*2;
  #pragma unroll
  for (int it = 0; it < 2; it++) {
    int t = tbase + it;
    float logit = lp[(size_t)t*N_EXP + lane]
                + lp[(size_t)T_TOKENS*N_EXP + (size_t)t*N_EXP + lane]
                + lp[2*(size_t)T_TOKENS*N_EXP + (size_t)t*N_EXP + lane];
    float prob = 1.f/(1.f + expf(-logit));
    pacc += prob;
    float mx = logit;
    for (int s = 32; s; s >>= 1) mx = fmaxf(mx, __shfl_xor(mx, s, 64));
    float sse = expf(logit - mx);
    for (int s = 32; s; s >>= 1) sse += __shfl_xor(sse, s, 64);
    float lse = mx + logf(sse);
    zacc += lse*lse;
    int rank = 0;
    #pragma unroll
    for (int j = 0; j < 64; j++) {
      float pj = __shfl(prob, j, 64);
      rank += (pj > prob || (pj == prob && j < lane)) ? 1 : 0;
    }
    bool sel = rank < TOPK;
    float sp = sel ? prob : 0.f;
    for (int s = 32; s; s >>= 1) sp += __shfl_xor(sp, s, 64);
    if (sel) {
      sel_e[t*TOPK + rank] = lane;
      sel_w[t*TOPK + rank] = prob / (sp + 1e-20f);
      cacc++;
    }
  }
  psum_s[wv][lane] = pacc;
  cnt_s[wv][lane] = cacc;
  if (lane == 0) atomicAdd(&scal[0], zacc);
  __syncthreads();
  if (tid < 64) {
    float p = psum_s[0][tid] + psum_s[1][tid] + psum_s[2][tid] + psum_s[3][tid];
    int c = cnt_s[0][tid] + cnt_s[1][tid] + cnt_s[2][tid] + cnt_s[3][tid];
    atomicAdd(&psum[tid], p);
    atomicAdd(&counts[tid], c);
  }
}

// ---------------- schedule: 64-row tiles, XCD-grouped positions ----------------
// expert e's tiles at positions p = (e%8) + 8*rank  => blocks p%8 share an XCD
__global__ void k_schedule(const int* __restrict__ counts, int* __restrict__ offsets,
                           int* __restrict__ sched_e, int* __restrict__ sched_r0) {
  int e = threadIdx.x;   // 64 threads, one wave
  int c = counts[e];
  int tiles = (c + 63) >> 6;
  int padded = tiles << 6;
  // exclusive prefix over padded -> row offsets
  int ip = padded;
  for (int s = 1; s < 64; s <<= 1) { int v = __shfl_up(ip, s, 64); if (e >= s) ip += v; }
  int rowoff = ip - padded;
  offsets[e] = rowoff;
  // within-XCD-group exclusive prefix of tile counts (stride-8 scan)
  int it = tiles;
  for (int s = 8; s < 64; s <<= 1) { int v = __shfl_up(it, s, 64); if (e >= s) it += v; }
  int rank = it - tiles;
  int xcd = e & 7;
  for (int i = 0; i < tiles; i++) {
    int p = xcd + 8*(rank + i);
    sched_e[p] = e;
    sched_r0[p] = rowoff + i*64;
  }
}

// ---------------- assign tokens to slots ----------------
__global__ void k_assign(const int* __restrict__ sel_e, const float* __restrict__ sel_w,
                         const int* __restrict__ offsets, int* __restrict__ cursor,
                         int* __restrict__ tok_slot, float* __restrict__ wgt_slot) {
  int i = blockIdx.x*256 + threadIdx.x;   // 16384
  int e = sel_e[i];
  int pos = atomicAdd(&cursor[e], 1);
  int slot = offsets[e] + pos;
  tok_slot[slot] = i >> 3;
  wgt_slot[slot] = sel_w[i];
}

// ---------------- grouped GEMM, 64x128 tile, BK=64, double-buffered 2-phase ----------------
// MODE 1: h[slot][:] = relu(x[tok] @ W1_e)^2 * gate   (K=768, N=256 via 2 n-chunks)
// MODE 2: out[tok][:] += h[slot][:] @ W2_e            (K=256, N=768 via 6 n-chunks, atomic)
template<int MODE>
__global__ __launch_bounds__(256) void k_moe_gemm(
    const __hip_bfloat16* __restrict__ Ab, const __hip_bfloat16* __restrict__ Bt,
    const int* __restrict__ sched_e, const int* __restrict__ sched_r0,
    const int* __restrict__ tok_slot, const float* __restrict__ wgt_slot,
    float* __restrict__ outp) {
  constexpr int NS = (MODE == 1) ? 12 : 4;   // K-steps of 64
  __shared__ __hip_bfloat16 As[2][64*64];
  __shared__ __hip_bfloat16 Bs[2][128*64];
  int tid = threadIdx.x;
  int nch = blockIdx.y;
  int arl = tid >> 3, akc = tid & 7;
  int a_off = ((akc ^ (arl & 7)) << 3);      // same for row arl and arl+32
  int b_off = a_off;                          // same (tid>>3, tid&7) pattern
  int wv = tid >> 6, lane = tid & 63;
  int wm = wv >> 1, wn = wv & 1;
  int l15 = lane & 15, l4 = lane >> 4;
  int b_str = (MODE == 1) ? D_EMBD : TW;

  for (int p = blockIdx.x; p < SCHED_MAX; p += gridDim.x) {
    int e = sched_e[p];
    if (e < 0) continue;
    int r0 = sched_r0[p];

    size_t a_base0, a_base1;
    if (MODE == 1) {
      a_base0 = (size_t)tok_slot[r0 + arl] * D_EMBD;
      a_base1 = (size_t)tok_slot[r0 + arl + 32] * D_EMBD;
    } else {
      a_base0 = (size_t)(r0 + arl) * EW;
      a_base1 = (size_t)(r0 + arl + 32) * EW;
    }
    size_t b_base = (MODE == 1) ? (size_t)(e*EW + nch*128) * D_EMBD
                                : (size_t)(nch*128) * TW + (size_t)e*EW;

    f32x4 acc[2][4];
    f32x4 z = {0.f, 0.f, 0.f, 0.f};
    #pragma unroll
    for (int m = 0; m < 2; m++)
      #pragma unroll
      for (int n = 0; n < 4; n++) acc[m][n] = z;

    auto STAGE = [&](int bsel, int k0) {
      GLOAD16(Ab + a_base0 + k0 + a_off, &As[bsel][0] + tid*8);
      GLOAD16(Ab + a_base1 + k0 + a_off, &As[bsel][0] + (256 + tid)*8);
      #pragma unroll
      for (int i = 0; i < 4; i++) {
        int br = i*32 + arl;
        GLOAD16(Bt + b_base + (size_t)br*b_str + k0 + b_off, &Bs[bsel][0] + (i*256 + tid)*8);
      }
    };

    int cur = 0;
    STAGE(0, 0);
    asm volatile("s_waitcnt vmcnt(0)" ::: "memory");
    __syncthreads();
    for (int step = 0; step < NS; step++) {
      if (step + 1 < NS) STAGE(cur ^ 1, (step + 1)*64);
      const bf16x8* A8 = reinterpret_cast<const bf16x8*>(&As[cur][0]);
      const bf16x8* B8 = reinterpret_cast<const bf16x8*>(&Bs[cur][0]);
      bf16x8 af[2][2], bq[4][2];
      #pragma unroll
      for (int m = 0; m < 2; m++) {
        int ra = wm*32 + m*16 + l15;
        #pragma unroll
        for (int kk = 0; kk < 2; kk++)
          af[m][kk] = A8[ra*8 + ((kk*4 + l4) ^ (ra & 7))];
      }
      #pragma unroll
      for (int n = 0; n < 4; n++) {
        int rb = wn*64 + n*16 + l15;
        #pragma unroll
        for (int kk = 0; kk < 2; kk++)
          bq[n][kk] = B8[rb*8 + ((kk*4 + l4) ^ (rb & 7))];
      }
      #pragma unroll
      for (int kk = 0; kk < 2; kk++)
        #pragma unroll
        for (int m = 0; m < 2; m++)
          #pragma unroll
          for (int n = 0; n < 4; n++)
            acc[m][n] = __builtin_amdgcn_mfma_f32_16x16x32_bf16(af[m][kk], bq[n][kk], acc[m][n], 0, 0, 0);
      asm volatile("s_waitcnt vmcnt(0)" ::: "memory");
      __syncthreads();
      cur ^= 1;
    }

    if (MODE == 1) {
      __hip_bfloat16* h = (__hip_bfloat16*)outp;
      #pragma unroll
      for (int m = 0; m < 2; m++)
        #pragma unroll
        for (int j = 0; j < 4; j++) {
          int r = r0 + wm*32 + m*16 + l4*4 + j;
          float wg = wgt_slot[r];
          #pragma unroll
          for (int n = 0; n < 4; n++) {
            int col = nch*128 + wn*64 + n*16 + l15;
            float v = fmaxf(acc[m][n][j], 0.f);
            h[(size_t)r*EW + col] = __float2bfloat16(v*v*wg);
          }
        }
    } else {
      #pragma unroll
      for (int m = 0; m < 2; m++)
        #pragma unroll
        for (int j = 0; j < 4; j++) {
          int tok = tok_slot[r0 + wm*32 + m*16 + l4*4 + j];
          #pragma unroll
          for (int n = 0; n < 4; n++) {
            int col = nch*128 + wn*64 + n*16 + l15;
            atomicAdd(&outp[(size_t)tok*D_EMBD + col], acc[m][n][j]);
          }
        }
    }
  }
}

// ---------------- aux losses + f_i ----------------
__global__ void k_finalize(const int* __restrict__ counts, const float* __restrict__ psum,
                           const float* __restrict__ scal, float* __restrict__ out) {
  __shared__ float part[N_EXP], ptot[N_EXP];
  int e = threadIdx.x;
  float f = (float)counts[e] / 16384.f;
  float p = psum[e] / 2048.f;
  part[e] = f * p;
  ptot[e] = p;
  out[OUT_BASE + 3 + e] = f;
  __syncthreads();
  if (e == 0) {
    float s = 0.f, q = 0.f;
    for (int i = 0; i < N_EXP; i++) { s += part[i]; q += ptot[i]; }
    out[OUT_BASE + 0] = scal[0] / 2048.f;      // router_z_loss
    out[OUT_BASE + 1] = 64.f * s;              // load_balance_loss
    out[OUT_BASE + 2] = q;                     // compute_loss
  }
}

extern "C" void kernel_launch(void* const* d_in, const int* in_sizes, int n_in,
                              void* d_out, int out_size, void* d_ws, size_t ws_size,
                              hipStream_t stream) {
  const float* x  = (const float*)d_in[0];
  const float* rw = (const float*)d_in[1];
  const float* w1 = (const float*)d_in[2];
  const float* w2 = (const float*)d_in[3];
  float* out = (float*)d_out;
  char* ws = (char*)d_ws;

  size_t o = 0;
  auto alloc = [&](size_t b) { size_t r = o; o += (b + 255) & ~(size_t)255; return r; };
  __hip_bfloat16* xb    = (__hip_bfloat16*)(ws + alloc(2048UL*768*2));
  __hip_bfloat16* w1t   = (__hip_bfloat16*)(ws + alloc(16384UL*768*2));
  __hip_bfloat16* w2t   = (__hip_bfloat16*)(ws + alloc(768UL*16384*2));
  __hip_bfloat16* hprm  = (__hip_bfloat16*)(ws + alloc((size_t)PAD_SLOTS*256*2));
  float* lp      = (float*)(ws + alloc(3UL*2048*64*4));
  int*   sel_e   = (int*)  (ws + alloc(16384UL*4));
  float* sel_w   = (float*)(ws + alloc(16384UL*4));
  int*   tokslot = (int*)  (ws + alloc((size_t)PAD_SLOTS*4));
  float* wgtslot = (float*)(ws + alloc((size_t)PAD_SLOTS*4));
  int*   counts  = (int*)  (ws + alloc(256));
  int*   cursor  = (int*)  (ws + alloc(256));
  float* psum    = (float*)(ws + alloc(256));
  float* scal    = (float*)(ws + alloc(256));
  int*   offsets = (int*)  (ws + alloc(256));
  int*   sch_e   = (int*)  (ws + alloc(SCHED_MAX*4));
  int*   sch_r0  = (int*)  (ws + alloc(SCHED_MAX*4));

  k_init<<<80, 256, 0, stream>>>(counts, cursor, psum, scal, wgtslot, tokslot, sch_e);
  k_zero_out<<<1536, 256, 0, stream>>>(out);
  k_cvt_x<<<1536, 256, 0, stream>>>(x, xb);
  k_transpose_cvt<<<dim3(256, 12, 2), 256, 0, stream>>>(w1, w1t, w2, w2t);
  k_logits<<<dim3(8, 8, 3), 256, 0, stream>>>(x, rw, lp);
  k_router2<<<256, 256, 0, stream>>>(lp, sel_e, sel_w, counts, psum, scal);
  k_schedule<<<1, 64, 0, stream>>>(counts, offsets, sch_e, sch_r0);
  k_assign<<<64, 256, 0, stream>>>(sel_e, sel_w, offsets, cursor, tokslot, wgtslot);
  k_moe_gemm<1><<<dim3(512, 2), 256, 0, stream>>>(xb, w1t, sch_e, sch_r0, tokslot, wgtslot, (float*)hprm);
  k_moe_gemm<2><<<dim3(512, 6), 256, 0, stream>>>(hprm, w2t, sch_e, sch_r0, tokslot, wgtslot, out);
  k_finalize<<<1, 64, 0, stream>>>(counts, psum, scal, out);
}

// Round 6
// 143.314 us; speedup vs baseline: 2.7407x; 2.7407x over previous
//
#include <hip/hip_runtime.h>
#include <hip/hip_bf16.h>

#define T_TOKENS 2048
#define D_EMBD 768
#define N_EXP 64
#define EW 256
#define TOPK 8
#define TW (N_EXP*EW)
#define PAD_SLOTS 20480   // 16384 + 64*63 rounded up to 64-tile granularity
#define SCHED_MAX 2560    // 8 * 320 worst-case positions, mult of 512
#define OUT_BASE (2048*768)

typedef __attribute__((ext_vector_type(8))) short bf16x8;
typedef __attribute__((ext_vector_type(4))) float f32x4;

typedef __attribute__((address_space(1))) void GAS;
typedef __attribute__((address_space(3))) void LAS;
#define GLOAD16(g, l) __builtin_amdgcn_global_load_lds((GAS*)(g), (LAS*)(l), 16, 0, 0)

// ---------------- init ----------------
__global__ void k_init(int* counts, int* cursor, float* psum, float* scal,
                       float* wgt_slot, int* tok_slot, int* sched_e) {
  int i = blockIdx.x*256 + threadIdx.x;   // 20480 threads
  if (i < N_EXP) { counts[i] = 0; cursor[i] = 0; psum[i] = 0.f; }
  if (i < 2) scal[i] = 0.f;
  if (i < PAD_SLOTS) { wgt_slot[i] = 0.f; tok_slot[i] = 0; }
  if (i < SCHED_MAX) sched_e[i] = -1;
}

// ---------------- x -> bf16 ----------------
__global__ void k_cvt_x(const float* __restrict__ x, __hip_bfloat16* __restrict__ xb) {
  int i = blockIdx.x*256 + threadIdx.x;   // 393216 float4
  float4 v = reinterpret_cast<const float4*>(x)[i];
  union { __hip_bfloat16 b; unsigned short u; } c0, c1, c2, c3;
  c0.b = __float2bfloat16(v.x); c1.b = __float2bfloat16(v.y);
  c2.b = __float2bfloat16(v.z); c3.b = __float2bfloat16(v.w);
  ushort4 o; o.x = c0.u; o.y = c1.u; o.z = c2.u; o.w = c3.u;
  reinterpret_cast<ushort4*>(xb)[i] = o;
}

// ---------------- transpose + convert, both weights in one launch ----------------
// z=0: w1 [768][16384] -> w1t [16384][768]; z=1: w2 [16384][768] -> w2t [768][16384]
__global__ __launch_bounds__(256) void k_transpose_cvt(
    const float* __restrict__ s1, __hip_bfloat16* __restrict__ d1,
    const float* __restrict__ s2, __hip_bfloat16* __restrict__ d2) {
  __shared__ float t[64][65];
  const float* src; __hip_bfloat16* dst; int R, C, bx, by;
  if (blockIdx.z == 0) { src = s1; dst = d1; R = 768; C = 16384;
                         bx = blockIdx.x*64; by = blockIdx.y*64; }
  else                 { src = s2; dst = d2; R = 16384; C = 768;
                         bx = blockIdx.y*64; by = blockIdx.x*64; }
  int tid = threadIdx.x;
  int lr = tid >> 4, lc4 = tid & 15;
  #pragma unroll
  for (int i = 0; i < 4; i++) {
    int r = lr + i*16;
    float4 v = *reinterpret_cast<const float4*>(&src[(size_t)(by+r)*C + bx + lc4*4]);
    t[r][lc4*4+0] = v.x; t[r][lc4*4+1] = v.y; t[r][lc4*4+2] = v.z; t[r][lc4*4+3] = v.w;
  }
  __syncthreads();
  int u = tid & 31, c0 = tid >> 5;
  #pragma unroll
  for (int i = 0; i < 8; i++) {
    int c = c0 + i*8;
    union { __hip_bfloat16 b; unsigned short us; } a0, a1;
    a0.b = __float2bfloat16(t[2*u][c]);
    a1.b = __float2bfloat16(t[2*u+1][c]);
    ushort2 o; o.x = a0.us; o.y = a1.us;
    *reinterpret_cast<ushort2*>(&dst[(size_t)(bx+c)*R + by + 2*u]) = o;
  }
}

// ---------------- router logits GEMM: lp[kc][t][e] partial sums ----------------
__global__ __launch_bounds__(256) void k_logits(const float* __restrict__ x,
                                                const float* __restrict__ rw,
                                                float* __restrict__ lp) {
  __shared__ float rw_s[8][256];
  int tid = threadIdx.x;
  int tg = blockIdx.x, eg = blockIdx.y, kc = blockIdx.z;
  #pragma unroll
  for (int idx = 0; idx < 8; idx++)
    rw_s[idx][tid] = rw[(size_t)(eg*8 + idx)*D_EMBD + kc*256 + tid];
  __syncthreads();
  int tok = tg*256 + tid;
  const float4* x4 = reinterpret_cast<const float4*>(x + (size_t)tok*D_EMBD + kc*256);
  float acc[8];
  #pragma unroll
  for (int e = 0; e < 8; e++) acc[e] = 0.f;
  #pragma unroll 4
  for (int k4 = 0; k4 < 64; k4++) {
    float4 xv = x4[k4];
    #pragma unroll
    for (int e = 0; e < 8; e++)
      acc[e] += xv.x*rw_s[e][k4*4+0] + xv.y*rw_s[e][k4*4+1]
              + xv.z*rw_s[e][k4*4+2] + xv.w*rw_s[e][k4*4+3];
  }
  float* dst = lp + (size_t)kc*T_TOKENS*N_EXP + (size_t)tok*N_EXP + eg*8;
  float4 o0 = {acc[0], acc[1], acc[2], acc[3]};
  float4 o1 = {acc[4], acc[5], acc[6], acc[7]};
  reinterpret_cast<float4*>(dst)[0] = o0;
  reinterpret_cast<float4*>(dst)[1] = o1;
}

// ---------------- router part 2: sigmoid, parallel-rank top-8, losses ----------------
__global__ __launch_bounds__(256) void k_router2(const float* __restrict__ lp,
                          int* __restrict__ sel_e, float* __restrict__ sel_w,
                          int* __restrict__ counts, float* __restrict__ psum,
                          float* __restrict__ scal) {
  __shared__ float psum_s[4][64];
  __shared__ int cnt_s[4][64];
  int tid = threadIdx.x, wv = tid >> 6, lane = tid & 63;
  float pacc = 0.f, zacc = 0.f;
  int cacc = 0;
  int tbase = blockIdx.x*8 + wv*2;
  #pragma unroll
  for (int it = 0; it < 2; it++) {
    int t = tbase + it;
    float logit = lp[(size_t)t*N_EXP + lane]
                + lp[(size_t)T_TOKENS*N_EXP + (size_t)t*N_EXP + lane]
                + lp[2*(size_t)T_TOKENS*N_EXP + (size_t)t*N_EXP + lane];
    float prob = 1.f/(1.f + expf(-logit));
    pacc += prob;
    float mx = logit;
    for (int s = 32; s; s >>= 1) mx = fmaxf(mx, __shfl_xor(mx, s, 64));
    float sse = expf(logit - mx);
    for (int s = 32; s; s >>= 1) sse += __shfl_xor(sse, s, 64);
    float lse = mx + logf(sse);
    zacc += lse*lse;
    int rank = 0;
    #pragma unroll
    for (int j = 0; j < 64; j++) {
      float pj = __shfl(prob, j, 64);
      rank += (pj > prob || (pj == prob && j < lane)) ? 1 : 0;
    }
    bool sel = rank < TOPK;
    float sp = sel ? prob : 0.f;
    for (int s = 32; s; s >>= 1) sp += __shfl_xor(sp, s, 64);
    if (sel) {
      sel_e[t*TOPK + rank] = lane;
      sel_w[t*TOPK + rank] = prob / (sp + 1e-20f);
      cacc++;
    }
  }
  psum_s[wv][lane] = pacc;
  cnt_s[wv][lane] = cacc;
  if (lane == 0) atomicAdd(&scal[0], zacc);
  __syncthreads();
  if (tid < 64) {
    float p = psum_s[0][tid] + psum_s[1][tid] + psum_s[2][tid] + psum_s[3][tid];
    int c = cnt_s[0][tid] + cnt_s[1][tid] + cnt_s[2][tid] + cnt_s[3][tid];
    atomicAdd(&psum[tid], p);
    atomicAdd(&counts[tid], c);
  }
}

// ---------------- schedule: 64-row tiles, XCD-grouped positions ----------------
__global__ void k_schedule(const int* __restrict__ counts, int* __restrict__ offsets,
                           int* __restrict__ sched_e, int* __restrict__ sched_r0) {
  int e = threadIdx.x;   // 64 threads, one wave
  int c = counts[e];
  int tiles = (c + 63) >> 6;
  int padded = tiles << 6;
  int ip = padded;
  for (int s = 1; s < 64; s <<= 1) { int v = __shfl_up(ip, s, 64); if (e >= s) ip += v; }
  int rowoff = ip - padded;
  offsets[e] = rowoff;
  int it = tiles;
  for (int s = 8; s < 64; s <<= 1) { int v = __shfl_up(it, s, 64); if (e >= s) it += v; }
  int rank = it - tiles;
  int xcd = e & 7;
  for (int i = 0; i < tiles; i++) {
    int p = xcd + 8*(rank + i);
    sched_e[p] = e;
    sched_r0[p] = rowoff + i*64;
  }
}

// ---------------- assign tokens to slots ----------------
__global__ void k_assign(const int* __restrict__ sel_e, const float* __restrict__ sel_w,
                         const int* __restrict__ offsets, int* __restrict__ cursor,
                         int* __restrict__ tok_slot, float* __restrict__ wgt_slot,
                         int* __restrict__ slot_tk) {
  int i = blockIdx.x*256 + threadIdx.x;   // 16384
  int e = sel_e[i];
  int pos = atomicAdd(&cursor[e], 1);
  int slot = offsets[e] + pos;
  tok_slot[slot] = i >> 3;
  wgt_slot[slot] = sel_w[i];
  slot_tk[i] = slot;
}

// ---------------- grouped GEMM, 64x128 tile, BK=64, double-buffered 2-phase ----------------
// MODE 1: h[slot][:] = relu(x[tok] @ W1_e)^2 * gate   (K=768, N=256 via 2 n-chunks)
// MODE 2: y[slot][:] = h[slot][:] @ W2_e              (K=256, N=768 via 6 n-chunks, bf16 store)
template<int MODE>
__global__ __launch_bounds__(256) void k_moe_gemm(
    const __hip_bfloat16* __restrict__ Ab, const __hip_bfloat16* __restrict__ Bt,
    const int* __restrict__ sched_e, const int* __restrict__ sched_r0,
    const int* __restrict__ tok_slot, const float* __restrict__ wgt_slot,
    __hip_bfloat16* __restrict__ outp) {
  constexpr int NS = (MODE == 1) ? 12 : 4;   // K-steps of 64
  __shared__ __hip_bfloat16 As[2][64*64];
  __shared__ __hip_bfloat16 Bs[2][128*64];
  int tid = threadIdx.x;
  int nch = blockIdx.y;
  int arl = tid >> 3, akc = tid & 7;
  int a_off = ((akc ^ (arl & 7)) << 3);
  int b_off = a_off;
  int wv = tid >> 6, lane = tid & 63;
  int wm = wv >> 1, wn = wv & 1;
  int l15 = lane & 15, l4 = lane >> 4;
  int b_str = (MODE == 1) ? D_EMBD : TW;

  for (int p = blockIdx.x; p < SCHED_MAX; p += gridDim.x) {
    int e = sched_e[p];
    if (e < 0) continue;
    int r0 = sched_r0[p];

    size_t a_base0, a_base1;
    if (MODE == 1) {
      a_base0 = (size_t)tok_slot[r0 + arl] * D_EMBD;
      a_base1 = (size_t)tok_slot[r0 + arl + 32] * D_EMBD;
    } else {
      a_base0 = (size_t)(r0 + arl) * EW;
      a_base1 = (size_t)(r0 + arl + 32) * EW;
    }
    size_t b_base = (MODE == 1) ? (size_t)(e*EW + nch*128) * D_EMBD
                                : (size_t)(nch*128) * TW + (size_t)e*EW;

    f32x4 acc[2][4];
    f32x4 z = {0.f, 0.f, 0.f, 0.f};
    #pragma unroll
    for (int m = 0; m < 2; m++)
      #pragma unroll
      for (int n = 0; n < 4; n++) acc[m][n] = z;

    auto STAGE = [&](int bsel, int k0) {
      GLOAD16(Ab + a_base0 + k0 + a_off, &As[bsel][0] + tid*8);
      GLOAD16(Ab + a_base1 + k0 + a_off, &As[bsel][0] + (256 + tid)*8);
      #pragma unroll
      for (int i = 0; i < 4; i++) {
        int br = i*32 + arl;
        GLOAD16(Bt + b_base + (size_t)br*b_str + k0 + b_off, &Bs[bsel][0] + (i*256 + tid)*8);
      }
    };

    int cur = 0;
    STAGE(0, 0);
    asm volatile("s_waitcnt vmcnt(0)" ::: "memory");
    __syncthreads();
    for (int step = 0; step < NS; step++) {
      if (step + 1 < NS) STAGE(cur ^ 1, (step + 1)*64);
      const bf16x8* A8 = reinterpret_cast<const bf16x8*>(&As[cur][0]);
      const bf16x8* B8 = reinterpret_cast<const bf16x8*>(&Bs[cur][0]);
      bf16x8 af[2][2], bq[4][2];
      #pragma unroll
      for (int m = 0; m < 2; m++) {
        int ra = wm*32 + m*16 + l15;
        #pragma unroll
        for (int kk = 0; kk < 2; kk++)
          af[m][kk] = A8[ra*8 + ((kk*4 + l4) ^ (ra & 7))];
      }
      #pragma unroll
      for (int n = 0; n < 4; n++) {
        int rb = wn*64 + n*16 + l15;
        #pragma unroll
        for (int kk = 0; kk < 2; kk++)
          bq[n][kk] = B8[rb*8 + ((kk*4 + l4) ^ (rb & 7))];
      }
      #pragma unroll
      for (int kk = 0; kk < 2; kk++)
        #pragma unroll
        for (int m = 0; m < 2; m++)
          #pragma unroll
          for (int n = 0; n < 4; n++)
            acc[m][n] = __builtin_amdgcn_mfma_f32_16x16x32_bf16(af[m][kk], bq[n][kk], acc[m][n], 0, 0, 0);
      asm volatile("s_waitcnt vmcnt(0)" ::: "memory");
      __syncthreads();
      cur ^= 1;
    }

    if (MODE == 1) {
      #pragma unroll
      for (int m = 0; m < 2; m++)
        #pragma unroll
        for (int j = 0; j < 4; j++) {
          int r = r0 + wm*32 + m*16 + l4*4 + j;
          float wg = wgt_slot[r];
          #pragma unroll
          for (int n = 0; n < 4; n++) {
            int col = nch*128 + wn*64 + n*16 + l15;
            float v = fmaxf(acc[m][n][j], 0.f);
            outp[(size_t)r*EW + col] = __float2bfloat16(v*v*wg);
          }
        }
    } else {
      #pragma unroll
      for (int m = 0; m < 2; m++)
        #pragma unroll
        for (int j = 0; j < 4; j++) {
          int r = r0 + wm*32 + m*16 + l4*4 + j;
          #pragma unroll
          for (int n = 0; n < 4; n++) {
            int col = nch*128 + wn*64 + n*16 + l15;
            outp[(size_t)r*D_EMBD + col] = __float2bfloat16(acc[m][n][j]);
          }
        }
    }
  }
}

// ---------------- combine 8 expert rows per token ----------------
__global__ void k_combine(const __hip_bfloat16* __restrict__ y, const int* __restrict__ slot_tk,
                          float* __restrict__ out) {
  __shared__ int s[TOPK];
  int t = blockIdx.x, tid = threadIdx.x;
  if (tid < TOPK) s[tid] = slot_tk[t*TOPK + tid];
  __syncthreads();
  for (int c = tid; c < D_EMBD; c += 256) {
    float a = 0.f;
    #pragma unroll
    for (int k = 0; k < TOPK; k++)
      a += __bfloat162float(y[(size_t)s[k]*D_EMBD + c]);
    out[(size_t)t*D_EMBD + c] = a;
  }
}

// ---------------- aux losses + f_i ----------------
__global__ void k_finalize(const int* __restrict__ counts, const float* __restrict__ psum,
                           const float* __restrict__ scal, float* __restrict__ out) {
  __shared__ float part[N_EXP], ptot[N_EXP];
  int e = threadIdx.x;
  float f = (float)counts[e] / 16384.f;
  float p = psum[e] / 2048.f;
  part[e] = f * p;
  ptot[e] = p;
  out[OUT_BASE + 3 + e] = f;
  __syncthreads();
  if (e == 0) {
    float s = 0.f, q = 0.f;
    for (int i = 0; i < N_EXP; i++) { s += part[i]; q += ptot[i]; }
    out[OUT_BASE + 0] = scal[0] / 2048.f;      // router_z_loss
    out[OUT_BASE + 1] = 64.f * s;              // load_balance_loss
    out[OUT_BASE + 2] = q;                     // compute_loss
  }
}

extern "C" void kernel_launch(void* const* d_in, const int* in_sizes, int n_in,
                              void* d_out, int out_size, void* d_ws, size_t ws_size,
                              hipStream_t stream) {
  const float* x  = (const float*)d_in[0];
  const float* rw = (const float*)d_in[1];
  const float* w1 = (const float*)d_in[2];
  const float* w2 = (const float*)d_in[3];
  float* out = (float*)d_out;
  char* ws = (char*)d_ws;

  size_t o = 0;
  auto alloc = [&](size_t b) { size_t r = o; o += (b + 255) & ~(size_t)255; return r; };
  __hip_bfloat16* xb    = (__hip_bfloat16*)(ws + alloc(2048UL*768*2));
  __hip_bfloat16* w1t   = (__hip_bfloat16*)(ws + alloc(16384UL*768*2));
  __hip_bfloat16* w2t   = (__hip_bfloat16*)(ws + alloc(768UL*16384*2));
  __hip_bfloat16* hprm  = (__hip_bfloat16*)(ws + alloc((size_t)PAD_SLOTS*256*2));
  __hip_bfloat16* yprm  = (__hip_bfloat16*)(ws + alloc((size_t)PAD_SLOTS*768*2));
  float* lp      = (float*)(ws + alloc(3UL*2048*64*4));
  int*   sel_e   = (int*)  (ws + alloc(16384UL*4));
  float* sel_w   = (float*)(ws + alloc(16384UL*4));
  int*   slot_tk = (int*)  (ws + alloc(16384UL*4));
  int*   tokslot = (int*)  (ws + alloc((size_t)PAD_SLOTS*4));
  float* wgtslot = (float*)(ws + alloc((size_t)PAD_SLOTS*4));
  int*   counts  = (int*)  (ws + alloc(256));
  int*   cursor  = (int*)  (ws + alloc(256));
  float* psum    = (float*)(ws + alloc(256));
  float* scal    = (float*)(ws + alloc(256));
  int*   offsets = (int*)  (ws + alloc(256));
  int*   sch_e   = (int*)  (ws + alloc(SCHED_MAX*4));
  int*   sch_r0  = (int*)  (ws + alloc(SCHED_MAX*4));

  k_init<<<80, 256, 0, stream>>>(counts, cursor, psum, scal, wgtslot, tokslot, sch_e);
  k_cvt_x<<<1536, 256, 0, stream>>>(x, xb);
  k_transpose_cvt<<<dim3(256, 12, 2), 256, 0, stream>>>(w1, w1t, w2, w2t);
  k_logits<<<dim3(8, 8, 3), 256, 0, stream>>>(x, rw, lp);
  k_router2<<<256, 256, 0, stream>>>(lp, sel_e, sel_w, counts, psum, scal);
  k_schedule<<<1, 64, 0, stream>>>(counts, offsets, sch_e, sch_r0);
  k_assign<<<64, 256, 0, stream>>>(sel_e, sel_w, offsets, cursor, tokslot, wgtslot, slot_tk);
  k_moe_gemm<1><<<dim3(512, 2), 256, 0, stream>>>(xb, w1t, sch_e, sch_r0, tokslot, wgtslot, hprm);
  k_moe_gemm<2><<<dim3(512, 6), 256, 0, stream>>>(hprm, w2t, sch_e, sch_r0, tokslot, wgtslot, yprm);
  k_combine<<<2048, 256, 0, stream>>>(yprm, slot_tk, out);
  k_finalize<<<1, 64, 0, stream>>>(counts, psum, scal, out);
}